// Round 5
// baseline (109.640 us; speedup 1.0000x reference)
//
#include <hip/hip_runtime.h>
#include <math.h>

#define N_SQ 64
#define TRUNCF 0.1f
#define EPSF 1e-6f
#define PTS_PER_BLOCK 128   // 256 threads: waves 0-1 -> j half 0, waves 2-3 -> j half 1

// --- fast hardware transcendentals (bases are guaranteed > 0 where used) ---
__device__ __forceinline__ float flog2(float x) { return __builtin_amdgcn_logf(x); }   // v_log_f32
__device__ __forceinline__ float fexp2(float x) { return __builtin_amdgcn_exp2f(x); }  // v_exp_f32
__device__ __forceinline__ float frcp(float x)  { return __builtin_amdgcn_rcpf(x); }   // v_rcp_f32
__device__ __forceinline__ float frsq(float x)  { return __builtin_amdgcn_rsqf(x); }   // v_rsq_f32

// Derived per-SQ parameter block: 5 x float4 (80 B), written to d_ws by prep_kernel.
//  [0] = R00,R01,R02,T0
//  [1] = R10,R11,R12,T1
//  [2] = R20,R21,R22,T2
//  [3] = iSx,iSy,iSz,c2e2   (c2e2 = 2/e2)
//  [4] = c2e1, mm, nh, 0    (c2e1 = 2/e1, mm = e2/e1, nh = -e1/2)
__global__ __launch_bounds__(64) void prep_kernel(
    const float* __restrict__ raw_scale,
    const float* __restrict__ raw_exp,
    const float* __restrict__ raw_rot,
    const float* __restrict__ trans,
    float4* __restrict__ params)
{
    const int j = threadIdx.x;
    if (j >= N_SQ) return;
    float qw = raw_rot[j * 4 + 0], qx = raw_rot[j * 4 + 1];
    float qy = raw_rot[j * 4 + 2], qz = raw_rot[j * 4 + 3];
    const float qn = sqrtf(qw * qw + qx * qx + qy * qy + qz * qz);
    qw /= qn; qx /= qn; qy /= qn; qz /= qn;
    const float e1 = 1.f / (1.f + expf(-raw_exp[j * 2 + 0])) * 1.8f + 0.1f;
    const float e2 = 1.f / (1.f + expf(-raw_exp[j * 2 + 1])) * 1.8f + 0.1f;
    params[j * 5 + 0] = make_float4(1.f - 2.f * (qy * qy + qz * qz),
                                    2.f * (qx * qy - qw * qz),
                                    2.f * (qx * qz + qw * qy),
                                    trans[j * 3 + 0]);
    params[j * 5 + 1] = make_float4(2.f * (qx * qy + qw * qz),
                                    1.f - 2.f * (qx * qx + qz * qz),
                                    2.f * (qy * qz - qw * qx),
                                    trans[j * 3 + 1]);
    params[j * 5 + 2] = make_float4(2.f * (qx * qz - qw * qy),
                                    2.f * (qy * qz + qw * qx),
                                    1.f - 2.f * (qx * qx + qy * qy),
                                    trans[j * 3 + 2]);
    params[j * 5 + 3] = make_float4(expf(-raw_scale[j * 3 + 0]),
                                    expf(-raw_scale[j * 3 + 1]),
                                    expf(-raw_scale[j * 3 + 2]),
                                    2.f / e2);
    params[j * 5 + 4] = make_float4(2.f / e1, e2 / e1, -e1 * 0.5f, 0.f);
}

// Pass-2: full gradient + normalize + store for one winning SQ.
// Op-for-op identical math to the round-2 kernel's gradient path.
__device__ __forceinline__ void write_winner(
    const float4* __restrict__ params,
    float px, float py, float pz, int jb, float best,
    float* __restrict__ out_sdf, float* __restrict__ out_nrm, int p)
{
    const float4 r0v = params[jb * 5 + 0];
    const float4 r1v = params[jb * 5 + 1];
    const float4 r2v = params[jb * 5 + 2];
    const float4 sc  = params[jb * 5 + 3];
    const float4 ex  = params[jb * 5 + 4];

    const float ux = px - r0v.w;
    const float uy = py - r1v.w;
    const float uz = pz - r2v.w;
    const float X0 = r0v.x * ux + r1v.x * uy + r2v.x * uz;
    const float X1 = r0v.y * ux + r1v.y * uy + r2v.y * uz;
    const float X2 = r0v.z * ux + r1v.z * uy + r2v.z * uz;

    const float a0 = fabsf(X0), a1 = fabsf(X1), a2 = fabsf(X2);
    const float ax = fmaxf(a0, EPSF);
    const float ay = fmaxf(a1, EPSF);
    const float az = fmaxf(a2, EPSF);
    const float sm0 = (a0 > EPSF) ? ((X0 > 0.f) ? 1.f : -1.f) : 0.f;
    const float sm1 = (a1 > EPSF) ? ((X1 > 0.f) ? 1.f : -1.f) : 0.f;
    const float sm2 = (a2 > EPSF) ? ((X2 > 0.f) ? 1.f : -1.f) : 0.f;

    const float r2 = ax * ax + ay * ay + az * az;
    const float inv_r0 = frsq(r2);
    const float r0 = r2 * inv_r0;

    const float t1 = fexp2(sc.w * flog2(ax * sc.x));
    const float t2 = fexp2(sc.w * flog2(ay * sc.y));
    const float t3 = fexp2(ex.x * flog2(az * sc.z));

    const float A = t1 + t2 + EPSF;
    const float B = fexp2(ex.y * flog2(A));
    const float S = B + t3;
    const float f = fexp2(ex.z * flog2(S));

    const float omf = 1.f - f;
    const float c1  = omf * inv_r0;
    const float w   = r0 * f * frcp(S);
    const float wBA = w * B * frcp(A);

    const float gmx = fmaf(wBA * t1, frcp(ax), c1 * ax);
    const float gmy = fmaf(wBA * t2, frcp(ay), c1 * ay);
    const float gmz = fmaf(w  * t3, frcp(az), c1 * az);
    const float gx = gmx * sm0;
    const float gy = gmy * sm1;
    const float gz = gmz * sm2;
    const float gpx = r0v.x * gx + r0v.y * gy + r0v.z * gz;
    const float gpy = r1v.x * gx + r1v.y * gy + r1v.z * gz;
    const float gpz = r2v.x * gx + r2v.y * gy + r2v.z * gz;

    const float n2 = gpx * gpx + gpy * gpy + gpz * gpz;
    const float inv_n = frsq(fmaxf(n2, 1e-24f));   // == 1/max(||g||,1e-12)

    out_sdf[p] = best;
    out_nrm[p * 3 + 0] = gpx * inv_n;
    out_nrm[p * 3 + 1] = gpy * inv_n;
    out_nrm[p * 3 + 2] = gpz * inv_n;
}

// j-split across wave pairs: block = 256 threads / 128 points.
// tid 0..127   -> point (base + tid),       j = 0..31
// tid 128..255 -> point (base + tid - 128), j = 32..63
// j stays wave-uniform -> params[] remain scalar (SMEM) loads.
// Grid doubles to 2048 blocks -> 8 blocks/CU = 32 waves/CU (max occupancy),
// halved per-wave dependent-chain length (latency-bound fix for R4 miss).
__global__ __launch_bounds__(256, 8) void superq_main(
    const float4* __restrict__ params,
    const float* __restrict__ points,
    float* __restrict__ out_sdf,
    float* __restrict__ out_nrm,
    int n_pts)
{
    __shared__ float sBest[256];
    __shared__ int   sJb[256];

    const int tid  = threadIdx.x;
    const int lid  = tid & (PTS_PER_BLOCK - 1);          // local point id 0..127
    const int half = tid >> 7;                           // 0 or 1 (wave-uniform)
    const int p    = blockIdx.x * PTS_PER_BLOCK + lid;
    const bool valid = p < n_pts;

    float px = 0.f, py = 0.f, pz = 0.f;
    if (valid) {
        px = points[p * 3 + 0];
        py = points[p * 3 + 1];
        pz = points[p * 3 + 2];
    }

    float best = INFINITY;
    int jb = half * (N_SQ / 2);
    const int j0 = half * (N_SQ / 2);

    // Pass 1: sdf-only argmin over this thread's 32 SQs. Math op-for-op
    // identical to round-2/3 sdf path (same values -> same argmin).
    #pragma unroll 4
    for (int jj = 0; jj < N_SQ / 2; ++jj) {
        const int j = j0 + jj;
        const float4 r0v = params[j * 5 + 0];
        const float4 r1v = params[j * 5 + 1];
        const float4 r2v = params[j * 5 + 2];
        const float4 sc  = params[j * 5 + 3];
        const float4 ex  = params[j * 5 + 4];

        const float ux = px - r0v.w;
        const float uy = py - r1v.w;
        const float uz = pz - r2v.w;
        const float X0 = r0v.x * ux + r1v.x * uy + r2v.x * uz;
        const float X1 = r0v.y * ux + r1v.y * uy + r2v.y * uz;
        const float X2 = r0v.z * ux + r1v.z * uy + r2v.z * uz;

        const float ax = fmaxf(fabsf(X0), EPSF);
        const float ay = fmaxf(fabsf(X1), EPSF);
        const float az = fmaxf(fabsf(X2), EPSF);

        const float r2 = ax * ax + ay * ay + az * az;
        const float inv_r0 = frsq(r2);
        const float r0 = r2 * inv_r0;

        const float t1 = fexp2(sc.w * flog2(ax * sc.x));
        const float t2 = fexp2(sc.w * flog2(ay * sc.y));
        const float t3 = fexp2(ex.x * flog2(az * sc.z));

        const float A = t1 + t2 + EPSF;
        const float B = fexp2(ex.y * flog2(A));
        const float S = B + t3;
        const float f = fexp2(ex.z * flog2(S));

        const float sdfc = fminf(fmaxf(r0 * (1.f - f), -TRUNCF), TRUNCF);
        const bool take = sdfc < best;   // strict <: first-min-wins within half
        best = take ? sdfc : best;
        jb   = take ? j : jb;
    }

    sBest[tid] = best;
    sJb[tid]   = jb;
    __syncthreads();

    // Merge halves + pass 2, threads 0..127 only. Lower j-half wins ties
    // (all its j are smaller), exactly matching jnp.argmin first-min.
    if (tid < PTS_PER_BLOCK && valid) {
        const float bl = sBest[tid];
        const float bh = sBest[tid + PTS_PER_BLOCK];
        const int   jl = sJb[tid];
        const int   jh = sJb[tid + PTS_PER_BLOCK];
        const bool hi_wins = bh < bl;        // strict: ties -> lower half
        const float bw = hi_wins ? bh : bl;
        const int   jw = hi_wins ? jh : jl;
        write_winner(params, px, py, pz, jw, bw, out_sdf, out_nrm, p);
    }
}

extern "C" void kernel_launch(void* const* d_in, const int* in_sizes, int n_in,
                              void* d_out, int out_size, void* d_ws, size_t ws_size,
                              hipStream_t stream) {
    const float* raw_scale = (const float*)d_in[0];
    const float* raw_exp   = (const float*)d_in[1];
    const float* raw_rot   = (const float*)d_in[2];
    const float* trans     = (const float*)d_in[3];
    const float* points    = (const float*)d_in[4];
    float* out = (float*)d_out;

    const int n_pts = in_sizes[4] / 3;
    float* out_sdf = out;            // [n_pts]
    float* out_nrm = out + n_pts;    // [n_pts, 3]

    float4* params = (float4*)d_ws;  // 64 * 5 * 16 B = 5120 B

    prep_kernel<<<1, 64, 0, stream>>>(raw_scale, raw_exp, raw_rot, trans, params);

    const int grid = (n_pts + PTS_PER_BLOCK - 1) / PTS_PER_BLOCK;
    superq_main<<<grid, 256, 0, stream>>>(params, points, out_sdf, out_nrm, n_pts);
}

// Round 6
// 92.138 us; speedup vs baseline: 1.1900x; 1.1900x over previous
//
#include <hip/hip_runtime.h>
#include <math.h>

#define N_SQ 64
#define TRUNCF 0.1f
#define EPSF 1e-6f
#define PTS_PER_BLOCK 128   // 256 threads: waves 0-1 -> j half 0, waves 2-3 -> j half 1

// --- fast hardware transcendentals (bases are guaranteed > 0 where used) ---
__device__ __forceinline__ float flog2(float x) { return __builtin_amdgcn_logf(x); }   // v_log_f32
__device__ __forceinline__ float fexp2(float x) { return __builtin_amdgcn_exp2f(x); }  // v_exp_f32
__device__ __forceinline__ float frcp(float x)  { return __builtin_amdgcn_rcpf(x); }   // v_rcp_f32
__device__ __forceinline__ float frsq(float x)  { return __builtin_amdgcn_rsqf(x); }   // v_rsq_f32

// Derived per-SQ parameter block: 5 x float4 (80 B), written to d_ws by prep_kernel.
//  [0] = R00,R01,R02,T0
//  [1] = R10,R11,R12,T1
//  [2] = R20,R21,R22,T2
//  [3] = iSx,iSy,iSz,c2e2   (c2e2 = 2/e2)
//  [4] = c2e1, mm, nh, 0    (c2e1 = 2/e1, mm = e2/e1, nh = -e1/2)
__global__ __launch_bounds__(64) void prep_kernel(
    const float* __restrict__ raw_scale,
    const float* __restrict__ raw_exp,
    const float* __restrict__ raw_rot,
    const float* __restrict__ trans,
    float4* __restrict__ params)
{
    const int j = threadIdx.x;
    if (j >= N_SQ) return;
    float qw = raw_rot[j * 4 + 0], qx = raw_rot[j * 4 + 1];
    float qy = raw_rot[j * 4 + 2], qz = raw_rot[j * 4 + 3];
    const float qn = sqrtf(qw * qw + qx * qx + qy * qy + qz * qz);
    qw /= qn; qx /= qn; qy /= qn; qz /= qn;
    const float e1 = 1.f / (1.f + expf(-raw_exp[j * 2 + 0])) * 1.8f + 0.1f;
    const float e2 = 1.f / (1.f + expf(-raw_exp[j * 2 + 1])) * 1.8f + 0.1f;
    params[j * 5 + 0] = make_float4(1.f - 2.f * (qy * qy + qz * qz),
                                    2.f * (qx * qy - qw * qz),
                                    2.f * (qx * qz + qw * qy),
                                    trans[j * 3 + 0]);
    params[j * 5 + 1] = make_float4(2.f * (qx * qy + qw * qz),
                                    1.f - 2.f * (qx * qx + qz * qz),
                                    2.f * (qy * qz - qw * qx),
                                    trans[j * 3 + 1]);
    params[j * 5 + 2] = make_float4(2.f * (qx * qz - qw * qy),
                                    2.f * (qy * qz + qw * qx),
                                    1.f - 2.f * (qx * qx + qy * qy),
                                    trans[j * 3 + 2]);
    params[j * 5 + 3] = make_float4(expf(-raw_scale[j * 3 + 0]),
                                    expf(-raw_scale[j * 3 + 1]),
                                    expf(-raw_scale[j * 3 + 2]),
                                    2.f / e2);
    params[j * 5 + 4] = make_float4(2.f / e1, e2 / e1, -e1 * 0.5f, 0.f);
}

// Pass-2: full gradient + normalize + store for one winning SQ.
// Op-for-op identical math to the round-2 kernel's gradient path.
__device__ __forceinline__ void write_winner(
    const float4* __restrict__ params,
    float px, float py, float pz, int jb, float best,
    float* __restrict__ out_sdf, float* __restrict__ out_nrm, int p)
{
    const float4 r0v = params[jb * 5 + 0];
    const float4 r1v = params[jb * 5 + 1];
    const float4 r2v = params[jb * 5 + 2];
    const float4 sc  = params[jb * 5 + 3];
    const float4 ex  = params[jb * 5 + 4];

    const float ux = px - r0v.w;
    const float uy = py - r1v.w;
    const float uz = pz - r2v.w;
    const float X0 = r0v.x * ux + r1v.x * uy + r2v.x * uz;
    const float X1 = r0v.y * ux + r1v.y * uy + r2v.y * uz;
    const float X2 = r0v.z * ux + r1v.z * uy + r2v.z * uz;

    const float a0 = fabsf(X0), a1 = fabsf(X1), a2 = fabsf(X2);
    const float ax = fmaxf(a0, EPSF);
    const float ay = fmaxf(a1, EPSF);
    const float az = fmaxf(a2, EPSF);
    const float sm0 = (a0 > EPSF) ? ((X0 > 0.f) ? 1.f : -1.f) : 0.f;
    const float sm1 = (a1 > EPSF) ? ((X1 > 0.f) ? 1.f : -1.f) : 0.f;
    const float sm2 = (a2 > EPSF) ? ((X2 > 0.f) ? 1.f : -1.f) : 0.f;

    const float r2 = ax * ax + ay * ay + az * az;
    const float inv_r0 = frsq(r2);
    const float r0 = r2 * inv_r0;

    const float t1 = fexp2(sc.w * flog2(ax * sc.x));
    const float t2 = fexp2(sc.w * flog2(ay * sc.y));
    const float t3 = fexp2(ex.x * flog2(az * sc.z));

    const float A = t1 + t2 + EPSF;
    const float B = fexp2(ex.y * flog2(A));
    const float S = B + t3;
    const float f = fexp2(ex.z * flog2(S));

    const float omf = 1.f - f;
    const float c1  = omf * inv_r0;
    const float w   = r0 * f * frcp(S);
    const float wBA = w * B * frcp(A);

    const float gmx = fmaf(wBA * t1, frcp(ax), c1 * ax);
    const float gmy = fmaf(wBA * t2, frcp(ay), c1 * ay);
    const float gmz = fmaf(w  * t3, frcp(az), c1 * az);
    const float gx = gmx * sm0;
    const float gy = gmy * sm1;
    const float gz = gmz * sm2;
    const float gpx = r0v.x * gx + r0v.y * gy + r0v.z * gz;
    const float gpy = r1v.x * gx + r1v.y * gy + r1v.z * gz;
    const float gpz = r2v.x * gx + r2v.y * gy + r2v.z * gz;

    const float n2 = gpx * gpx + gpy * gpy + gpz * gpz;
    const float inv_n = frsq(fmaxf(n2, 1e-24f));   // == 1/max(||g||,1e-12)

    out_sdf[p] = best;
    out_nrm[p * 3 + 0] = gpx * inv_n;
    out_nrm[p * 3 + 1] = gpy * inv_n;
    out_nrm[p * 3 + 2] = gpz * inv_n;
}

// j-split across wave pairs: block = 256 threads / 128 points.
// tid 0..127   -> point (base + tid),       j = 0..31
// tid 128..255 -> point (base + tid - 128), j = 32..63
// CRITICAL (R5 lesson): the compiler's divergence analysis treats tid>>7 as
// divergent, turning params[] into per-lane vector loads (vmcnt stalls,
// VALUBusy 75->48%). readfirstlane forces j0 into an SGPR so the loop index
// is provably uniform -> params stay scalar s_load (SMEM pipe).
__global__ __launch_bounds__(256, 8) void superq_main(
    const float4* __restrict__ params,
    const float* __restrict__ points,
    float* __restrict__ out_sdf,
    float* __restrict__ out_nrm,
    int n_pts)
{
    __shared__ float sBest[256];
    __shared__ int   sJb[256];

    const int tid  = threadIdx.x;
    const int lid  = tid & (PTS_PER_BLOCK - 1);          // local point id 0..127
    const int half = tid >> 7;                           // 0 or 1 (wave-uniform)
    const int p    = blockIdx.x * PTS_PER_BLOCK + lid;
    const bool valid = p < n_pts;

    float px = 0.f, py = 0.f, pz = 0.f;
    if (valid) {
        px = points[p * 3 + 0];
        py = points[p * 3 + 1];
        pz = points[p * 3 + 2];
    }

    // Force SGPR: wave-uniform j base (see comment above).
    const int j0 = __builtin_amdgcn_readfirstlane(half * (N_SQ / 2));

    float best = INFINITY;
    int jb = j0;

    // Pass 1: sdf-only argmin over this thread's 32 SQs. Math op-for-op
    // identical to round-2/3 sdf path (same values -> same argmin).
    #pragma unroll 4
    for (int jj = 0; jj < N_SQ / 2; ++jj) {
        const int j = j0 + jj;
        const float4 r0v = params[j * 5 + 0];
        const float4 r1v = params[j * 5 + 1];
        const float4 r2v = params[j * 5 + 2];
        const float4 sc  = params[j * 5 + 3];
        const float4 ex  = params[j * 5 + 4];

        const float ux = px - r0v.w;
        const float uy = py - r1v.w;
        const float uz = pz - r2v.w;
        const float X0 = r0v.x * ux + r1v.x * uy + r2v.x * uz;
        const float X1 = r0v.y * ux + r1v.y * uy + r2v.y * uz;
        const float X2 = r0v.z * ux + r1v.z * uy + r2v.z * uz;

        const float ax = fmaxf(fabsf(X0), EPSF);
        const float ay = fmaxf(fabsf(X1), EPSF);
        const float az = fmaxf(fabsf(X2), EPSF);

        const float r2 = ax * ax + ay * ay + az * az;
        const float inv_r0 = frsq(r2);
        const float r0 = r2 * inv_r0;

        const float t1 = fexp2(sc.w * flog2(ax * sc.x));
        const float t2 = fexp2(sc.w * flog2(ay * sc.y));
        const float t3 = fexp2(ex.x * flog2(az * sc.z));

        const float A = t1 + t2 + EPSF;
        const float B = fexp2(ex.y * flog2(A));
        const float S = B + t3;
        const float f = fexp2(ex.z * flog2(S));

        const float sdfc = fminf(fmaxf(r0 * (1.f - f), -TRUNCF), TRUNCF);
        const bool take = sdfc < best;   // strict <: first-min-wins within half
        best = take ? sdfc : best;
        jb   = take ? j : jb;
    }

    sBest[tid] = best;
    sJb[tid]   = jb;
    __syncthreads();

    // Merge halves + pass 2, threads 0..127 only. Lower j-half wins ties
    // (all its j are smaller), exactly matching jnp.argmin first-min.
    if (tid < PTS_PER_BLOCK && valid) {
        const float bl = sBest[tid];
        const float bh = sBest[tid + PTS_PER_BLOCK];
        const int   jl = sJb[tid];
        const int   jh = sJb[tid + PTS_PER_BLOCK];
        const bool hi_wins = bh < bl;        // strict: ties -> lower half
        const float bw = hi_wins ? bh : bl;
        const int   jw = hi_wins ? jh : jl;
        write_winner(params, px, py, pz, jw, bw, out_sdf, out_nrm, p);
    }
}

extern "C" void kernel_launch(void* const* d_in, const int* in_sizes, int n_in,
                              void* d_out, int out_size, void* d_ws, size_t ws_size,
                              hipStream_t stream) {
    const float* raw_scale = (const float*)d_in[0];
    const float* raw_exp   = (const float*)d_in[1];
    const float* raw_rot   = (const float*)d_in[2];
    const float* trans     = (const float*)d_in[3];
    const float* points    = (const float*)d_in[4];
    float* out = (float*)d_out;

    const int n_pts = in_sizes[4] / 3;
    float* out_sdf = out;            // [n_pts]
    float* out_nrm = out + n_pts;    // [n_pts, 3]

    float4* params = (float4*)d_ws;  // 64 * 5 * 16 B = 5120 B

    prep_kernel<<<1, 64, 0, stream>>>(raw_scale, raw_exp, raw_rot, trans, params);

    const int grid = (n_pts + PTS_PER_BLOCK - 1) / PTS_PER_BLOCK;
    superq_main<<<grid, 256, 0, stream>>>(params, points, out_sdf, out_nrm, n_pts);
}